// Round 4
// baseline (104.846 us; speedup 1.0000x reference)
//
#include <hip/hip_runtime.h>
#include <cstddef>
#include <cstdint>

#define FN_ 100000
#define V_  50000
#define B_  8
#define NT  128
#define NBX 782                       // ceil(FN_/NT); last block has 32 valid cols

// d_ws layout (bytes): 48 weight tiles of 1 KB (fragment order), then shs f32[448]
//   tiles  0..15 : combined L1 weights (256x32, BN-scale folded, scatter layout)
//                  tile t covers rows [16t,16t+16): 0-63 c1, 64-127 e0, 128-191 e1, 192-255 e2
//   tiles 16..23 : c2 weights (64x64)        tile = 16 + 2*rt + s
//   tiles 24..31 : v2 weights (64x64, x1/3)  tile = 24 + 2*rt + s
//   tiles 32..47 : s  weights (64x128)       tile = 32 + 4*rt + s
#define WS_SHS 49152

typedef _Float16 f16;
typedef f16   f16x8 __attribute__((ext_vector_type(8)));
typedef float f32x4 __attribute__((ext_vector_type(4)));

struct Ptrs { const void* p[33]; };

union Pk4 { f16 h[4]; uint2 u; };
union Pk8 { f16 h[8]; uint4 u; };

// ---------------- prep: fold BN into f16 weights, fragment-ordered (unchanged, validated) ----------------
__global__ __launch_bounds__(1024) void sd_prep(Ptrs in, f16* __restrict__ wsW,
                                                float* __restrict__ shsG)
{
  const float* __restrict__ cw1 = (const float*)in.p[3];
  const float* __restrict__ cb1 = (const float*)in.p[4];
  const float* __restrict__ c1g = (const float*)in.p[5];
  const float* __restrict__ c1bt= (const float*)in.p[6];
  const float* __restrict__ c1m = (const float*)in.p[7];
  const float* __restrict__ c1v = (const float*)in.p[8];
  const float* __restrict__ cw2 = (const float*)in.p[9];
  const float* __restrict__ cb2 = (const float*)in.p[10];
  const float* __restrict__ c2g = (const float*)in.p[11];
  const float* __restrict__ c2bt= (const float*)in.p[12];
  const float* __restrict__ c2m = (const float*)in.p[13];
  const float* __restrict__ c2v = (const float*)in.p[14];
  const float* __restrict__ vw1 = (const float*)in.p[15];
  const float* __restrict__ vb1 = (const float*)in.p[16];
  const float* __restrict__ v1g = (const float*)in.p[17];
  const float* __restrict__ v1bt= (const float*)in.p[18];
  const float* __restrict__ v1m = (const float*)in.p[19];
  const float* __restrict__ v1v = (const float*)in.p[20];
  const float* __restrict__ vw2 = (const float*)in.p[21];
  const float* __restrict__ vb2 = (const float*)in.p[22];
  const float* __restrict__ v2g = (const float*)in.p[23];
  const float* __restrict__ v2bt= (const float*)in.p[24];
  const float* __restrict__ v2m = (const float*)in.p[25];
  const float* __restrict__ v2v = (const float*)in.p[26];
  const float* __restrict__ sw  = (const float*)in.p[27];
  const float* __restrict__ sb  = (const float*)in.p[28];
  const float* __restrict__ s1g = (const float*)in.p[29];
  const float* __restrict__ s1bt= (const float*)in.p[30];
  const float* __restrict__ s1m = (const float*)in.p[31];
  const float* __restrict__ s1v = (const float*)in.p[32];

  __shared__ float scsL[448];
  const int tid = threadIdx.x;

  if (tid < 448) {
    const float *g, *v, *bb, *m, *bt; int o; float mul = 1.f;
    if (tid < 64)       { o = tid;      g=c1g; v=c1v; bb=cb1; m=c1m; bt=c1bt; }
    else if (tid < 256) { o = tid & 63; g=v1g; v=v1v; bb=vb1; m=v1m; bt=v1bt; }
    else if (tid < 320) { o = tid-256;  g=c2g; v=c2v; bb=cb2; m=c2m; bt=c2bt; }
    else if (tid < 384) { o = tid-320;  g=v2g; v=v2v; bb=vb2; m=v2m; bt=v2bt; mul = 1.f/3.f; }
    else                { o = tid-384;  g=s1g; v=s1v; bb=sb;  m=s1m; bt=s1bt; }
    float s = g[o] * rsqrtf(v[o] + 1e-5f);
    scsL[tid] = s * mul;
    shsG[tid] = ((bb[o] - m[o]) * s + bt[o]) * mul;
  }
  __syncthreads();

  for (int u = tid; u < 3072; u += 1024) {
    const int t = u >> 6, l = u & 63, r15 = l & 15, g4 = l >> 4;
    Pk8 pk;
    if (t < 16) {                                   // L1 combined 256x32
      const int wm = t >> 2, tr = t & 3, row = 64*wm + 16*tr + r15;
#pragma unroll
      for (int j = 0; j < 8; ++j) {
        const int k = 8*g4 + j; float val = 0.f;
        if (wm == 0) { if (k >= 9 && k < 12) val = cw1[row*3 + (k-9)]; }
        else if (k < 9) {
          const int e = wm - 1, o = row - 64*wm, c = (k - 3*e + 9) % 9;
          if (c < 6) val = vw1[o*6 + c];
        }
        pk.h[j] = (f16)(val * scsL[row]);
      }
    } else if (t < 24) {                            // c2
      const int tt = t-16, rt = tt >> 1, s = tt & 1, row = 16*rt + r15;
#pragma unroll
      for (int j = 0; j < 8; ++j) { const int k = 32*s + 8*g4 + j;
        pk.h[j] = (f16)(cw2[row*64 + k] * scsL[256+row]); }
    } else if (t < 32) {                            // v2 (x 1/3)
      const int tt = t-24, rt = tt >> 1, s = tt & 1, row = 16*rt + r15;
#pragma unroll
      for (int j = 0; j < 8; ++j) { const int k = 32*s + 8*g4 + j;
        pk.h[j] = (f16)(vw2[row*64 + k] * scsL[320+row]); }
    } else {                                        // s (64x128)
      const int tt = t-32, rt = tt >> 2, s = tt & 3, row = 16*rt + r15;
#pragma unroll
      for (int j = 0; j < 8; ++j) { const int k = 32*s + 8*g4 + j;
        pk.h[j] = (f16)(sw[row*128 + k] * scsL[384+row]); }
    }
    *(uint4*)(wsW + (size_t)t*512 + l*8) = pk.u;
  }
}

// ---------------- main ----------------
// 3 blocks/CU (44.8 KB LDS). Phases:
//  gather |1| L1a(c1+e0 -> k0..127) |2| L2a(c2->cf, v2 e0->vf) |3|
//  L1b(e1+e2) |4| L2b(v2 e1,e2->vf) |5| cv write |6| L3 -> stores
__global__ __launch_bounds__(512, 6) void sd_main(const int* __restrict__ faces,
    const float* __restrict__ verts, const float* __restrict__ centers,
    const f16* __restrict__ wsW, const float* __restrict__ shsG,
    float* __restrict__ out)
{
  // Hs[col][k]: k 0..127 activations (h1-half / cv), 128..159 X, 160..167 pad
  // row stride 336 B = 84 dw ≡ 20 (mod 32) -> 2-way bank aliasing (free, m136)
  __shared__ f16 Hs[NT][168];
  __shared__ float shsL[448];

  const int tid  = threadIdx.x;
  const int lane = tid & 63;
  const int r15  = lane & 15;
  const int g4   = lane >> 4;
  const int wid  = __builtin_amdgcn_readfirstlane(tid >> 6);
  const int rt   = wid & 3;          // row-tile-group (rows 16*(2rt)+.. for L1, 16*rt for L2/L3)
  const int cg   = wid >> 2;         // col group of 64

  const int by   = blockIdx.y;
  const int col0 = blockIdx.x * NT;

  if (tid < 448) shsL[tid] = shsG[tid];

  // ---- gather X ----
  {
    const int col = tid >> 2, p = tid & 3;
    const int f = col0 + col;
    const bool valid = f < FN_;
    if (p < 3) {
      float x0 = 0.f, x1 = 0.f, x2 = 0.f;
      if (valid) {
        const int vi = faces[((size_t)by*FN_ + f)*3 + p];
        const float* vp = verts + ((size_t)by*V_ + (size_t)vi)*3;
        x0 = vp[0]; x1 = vp[1]; x2 = vp[2];
      }
      Hs[col][128 + p*3 + 0] = (f16)x0;
      Hs[col][128 + p*3 + 1] = (f16)x1;
      Hs[col][128 + p*3 + 2] = (f16)x2;
    } else {
#pragma unroll
      for (int k = 0; k < 3; ++k)
        Hs[col][137 + k] = valid ? (f16)centers[((size_t)by*3 + k)*FN_ + f] : (f16)0.f;
    }
#pragma unroll
    for (int z = 0; z < 5; ++z) Hs[col][140 + p*5 + z] = (f16)0.f;
  }
  __syncthreads();

  float cf[4][4], vf[4][4];
  f16x8 w2v[2];                      // v2 A-frags, loaded in L2a, reused in L2b (x2)

  // ================== half h = 0, 1 ==================
#pragma unroll
  for (int h = 0; h < 2; ++h) {
    // ---- L1 half: W1 tiles 8h+2rt+{0,1}, rows -> Hs k0..127 ----
    {
      f16x8 bfr[4];
#pragma unroll
      for (int tc = 0; tc < 4; ++tc)
        bfr[tc] = *(const f16x8*)&Hs[64*cg + 16*tc + r15][128 + 8*g4];
#pragma unroll
      for (int tr = 0; tr < 2; ++tr) {
        const int t16 = 2*rt + tr;                      // local row-tile 0..7
        const f16x8 a = *(const f16x8*)(wsW + (size_t)(8*h + t16)*512 + lane*8);
        const f32x4 shv = *(const f32x4*)&shsL[128*h + t16*16 + 4*g4];
#pragma unroll
        for (int tc = 0; tc < 4; ++tc) {
          f32x4 acc = shv;                              // bias via C-in
          acc = __builtin_amdgcn_mfma_f32_16x16x32_f16(a, bfr[tc], acc, 0,0,0);
          Pk4 pk;
#pragma unroll
          for (int j = 0; j < 4; ++j) pk.h[j] = (f16)fmaxf(acc[j], 0.f);
          *(uint2*)&Hs[64*cg + 16*tc + r15][t16*16 + 4*g4] = pk.u;
        }
      }
    }
    __syncthreads();

    // ---- L2 half: two branches; h==0: (c2 -> cf), (v2 -> vf); h==1: (v2 -> vf) x2 ----
#pragma unroll
    for (int sub = 0; sub < 2; ++sub) {
      const bool is_cf = (h == 0) && (sub == 0);
      f16x8 wa[2];
      if (is_cf) {
#pragma unroll
        for (int s = 0; s < 2; ++s)
          wa[s] = *(const f16x8*)(wsW + (size_t)(16 + 2*rt + s)*512 + lane*8);
      } else if (h == 0) {
#pragma unroll
        for (int s = 0; s < 2; ++s) {
          w2v[s] = *(const f16x8*)(wsW + (size_t)(24 + 2*rt + s)*512 + lane*8);
          wa[s] = w2v[s];
        }
      } else {
#pragma unroll
        for (int s = 0; s < 2; ++s) wa[s] = w2v[s];
      }
      const f32x4 shv = is_cf ? *(const f32x4*)&shsL[256 + rt*16 + 4*g4]
                              : *(const f32x4*)&shsL[320 + rt*16 + 4*g4];
      f32x4 acc[4];
#pragma unroll
      for (int tc = 0; tc < 4; ++tc) acc[tc] = shv;
#pragma unroll
      for (int s = 0; s < 2; ++s) {
#pragma unroll
        for (int tc = 0; tc < 4; ++tc) {
          const f16x8 b = *(const f16x8*)&Hs[64*cg + 16*tc + r15][64*sub + 32*s + 8*g4];
          acc[tc] = __builtin_amdgcn_mfma_f32_16x16x32_f16(wa[s], b, acc[tc], 0,0,0);
        }
      }
#pragma unroll
      for (int tc = 0; tc < 4; ++tc)
#pragma unroll
        for (int j = 0; j < 4; ++j) {
          const float val = fmaxf(acc[tc][j], 0.f);
          if (is_cf)       cf[tc][j]  = val;
          else if (h == 0 && sub == 1) vf[tc][j]  = val;
          else             vf[tc][j] += val;
        }
    }
    __syncthreads();   // h=0: L1b will overwrite k0..127 ; h=1: cv write below
  }

  // ---- cv write: cfeat -> k0..63, vfeat -> k64..127 ----
#pragma unroll
  for (int tc = 0; tc < 4; ++tc) {
    const int o0  = rt*16 + 4*g4;
    const int col = 64*cg + 16*tc + r15;
    Pk4 pc, pv;
#pragma unroll
    for (int j = 0; j < 4; ++j) { pc.h[j] = (f16)cf[tc][j]; pv.h[j] = (f16)vf[tc][j]; }
    *(uint2*)&Hs[col][o0]      = pc.u;
    *(uint2*)&Hs[col][64 + o0] = pv.u;
  }
  __syncthreads();

  // ---- L3: Ws[64x128] x cv -> out ----
  {
    const f32x4 shv = *(const f32x4*)&shsL[384 + rt*16 + 4*g4];
    f32x4 acc[4];
#pragma unroll
    for (int tc = 0; tc < 4; ++tc) acc[tc] = shv;
#pragma unroll
    for (int s = 0; s < 4; ++s) {
      const f16x8 a = *(const f16x8*)(wsW + (size_t)(32 + rt*4 + s)*512 + lane*8);
#pragma unroll
      for (int tc = 0; tc < 4; ++tc) {
        const f16x8 b = *(const f16x8*)&Hs[64*cg + 16*tc + r15][32*s + 8*g4];
        acc[tc] = __builtin_amdgcn_mfma_f32_16x16x32_f16(a, b, acc[tc], 0,0,0);
      }
    }
    const int o0 = rt*16 + 4*g4;
#pragma unroll
    for (int tc = 0; tc < 4; ++tc) {
      const int f = col0 + 64*cg + 16*tc + r15;
      if (f < FN_) {
        const size_t base = ((size_t)(by*64 + o0))*FN_ + f;
#pragma unroll
        for (int j = 0; j < 4; ++j)
          out[base + (size_t)j*FN_] = fmaxf(acc[tc][j], 0.f);
      }
    }
  }
}

extern "C" void kernel_launch(void* const* d_in, const int* in_sizes, int n_in,
                              void* d_out, int out_size, void* d_ws, size_t ws_size,
                              hipStream_t stream) {
  (void)in_sizes; (void)n_in; (void)out_size; (void)ws_size;
  Ptrs p;
  for (int i = 0; i < 33; ++i) p.p[i] = d_in[i];
  f16*   wsW  = (f16*)d_ws;
  float* shsG = (float*)((char*)d_ws + WS_SHS);
  hipLaunchKernelGGL(sd_prep, dim3(1), dim3(1024), 0, stream, p, wsW, shsG);
  hipLaunchKernelGGL(sd_main, dim3(NBX, B_), dim3(512), 0, stream,
                     (const int*)d_in[2], (const float*)d_in[1], (const float*)d_in[0],
                     wsW, shsG, (float*)d_out);
}